// Round 6
// baseline (244.417 us; speedup 1.0000x reference)
//
#include <hip/hip_runtime.h>
#include <hip/hip_bf16.h>
#include <stdint.h>

#define DEVINL __device__ __forceinline__

using bf16x8 = __attribute__((ext_vector_type(8))) short;
using f32x4  = __attribute__((ext_vector_type(4))) float;

static constexpr int NPTS = 50000;
static constexpr int NPAD = 50176;         // 392 * 128
static constexpr int DIM  = 768;
static constexpr int DATT = 128;
static constexpr int NRB  = NPAD / 128;    // 392 row blocks (gate / partial)
static constexpr int NSMB = 49;            // softmax partial blocks (49*1024 = 50176)

DEVINL ushort f2b(float f) {               // RNE float->bf16 (finite inputs)
  uint32_t u = __float_as_uint(f);
  u += 0x7fffu + ((u >> 16) & 1u);
  return (ushort)(u >> 16);
}
DEVINL float b2f(ushort u) { return __uint_as_float(((uint32_t)u) << 16); }

DEVINL void gload_lds16(const void* g, void* l) {
  __builtin_amdgcn_global_load_lds((const __attribute__((address_space(1))) void*)g,
                                   (__attribute__((address_space(3))) void*)l,
                                   16, 0, 0);
}

DEVINL uint32_t cvtpk(float lo, float hi) {
  union { __hip_bfloat162 h2; uint32_t u; } c;
  c.h2 = __float22bfloat162_rn(float2{lo, hi});
  return c.u;
}
DEVINL bf16x8 pack8(f32x4 lo, f32x4 hi) {
  union { uint32_t u[4]; bf16x8 v; } r;
  r.u[0] = cvtpk(lo[0], lo[1]);
  r.u[1] = cvtpk(lo[2], lo[3]);
  r.u[2] = cvtpk(hi[0], hi[1]);
  r.u[3] = cvtpk(hi[2], hi[3]);
  return r.v;
}

// ---------------- K0b: fp32 -> bf16 for the three weight matrices (one launch)
__global__ void cvt_weights_kernel(const float* __restrict__ Wf, const float* __restrict__ Wa,
                                   const float* __restrict__ Wb,
                                   ushort* __restrict__ wfb, ushort* __restrict__ wab,
                                   ushort* __restrict__ wbb) {
  const int NF = DIM * DIM / 8, NA = DATT * DIM / 8;
  int i = blockIdx.x * blockDim.x + threadIdx.x;
  const float* src; ushort* dst; int j;
  if (i < NF)               { src = Wf; dst = wfb; j = i; }
  else if (i < NF + NA)     { src = Wa; dst = wab; j = i - NF; }
  else if (i < NF + 2 * NA) { src = Wb; dst = wbb; j = i - NF - NA; }
  else return;
  const float4* s4 = (const float4*)src;
  float4 v0 = s4[(long)j * 2];
  float4 v1 = s4[(long)j * 2 + 1];
  ushort4 o0 = { f2b(v0.x), f2b(v0.y), f2b(v0.z), f2b(v0.w) };
  ushort4 o1 = { f2b(v1.x), f2b(v1.y), f2b(v1.z), f2b(v1.w) };
  ((ushort4*)dst)[(long)j * 2]     = o0;
  ((ushort4*)dst)[(long)j * 2 + 1] = o1;
}

// ---------------- K1: h = relu(x @ Wf^T + bias), fused fp32->bf16 on A --------
// BM=128, BN=128, BK=64; 8 waves (4M x 2N), wave tile 32x64.
// R3's proven pipeline: triple-buffered LDS (3 x 48KB), stage(t+2) ahead,
// counted vmcnt(12) (6 gload_lds/thread/stage, 2 stages in flight), raw
// s_barriers. A staged fp32 via global_load_lds (zero staging VGPRs, swizzled
// source), converted bf16 at fragment read (ds_read_b128 x2 + cvt_pk x4).
// Per buffer: A fp32 [128][64] = 32KB @0, B bf16 [128][64] = 16KB @32768.
__global__ __launch_bounds__(512)
void gemm_h_fused(const float* __restrict__ X, const ushort* __restrict__ Wfb,
                  const float* __restrict__ bias, ushort* __restrict__ H) {
  __shared__ char lds[3][49152];

  const int tid  = threadIdx.x;
  const int wid  = tid >> 6;           // 0..7
  const int lane = tid & 63;

  const int bid  = blockIdx.x;                       // 0..2351
  const int wgid = (bid & 7) * 294 + (bid >> 3);     // chunked XCD swizzle (2352%8==0)
  const int row0 = (wgid / 6) * 128;
  const int col0 = (wgid % 6) * 128;

  const int wrow = (wid >> 1) * 32;    // 0,32,64,96
  const int wcol = (wid & 1) * 64;     // 0,64

  f32x4 acc[2][4] = {};

  // staging geometry (LDS dests wave-uniform; swizzle on the global source)
  const int rA   = wid * 4 + (lane >> 4);            // A row within pass (0..31)
  const int swzA = ((lane & 15) ^ (rA & 7)) * 4;     // fp32 col offset (16B gran)
  const int rB   = wid * 8 + (lane >> 3);            // B row within pass (0..63)
  const int swzB = ((lane & 7) ^ (rB & 7)) * 8;      // bf16 col offset (16B gran)

  auto STAGE = [&](int t, int buf) {                 // 6 gload_lds per thread
    const int k0 = t * 64;
    char* base = &lds[buf][0];
#pragma unroll
    for (int i = 0; i < 4; ++i) {      // A: 4 passes x 32 rows (fp32, 32KB)
      const int rg  = row0 + i * 32 + rA;
      const int src = rg < NPTS ? rg : NPTS - 1;     // clamp; masked downstream
      gload_lds16(X + (long)src * DIM + k0 + swzA, base + (i * 32 + wid * 4) * 256);
    }
#pragma unroll
    for (int i = 0; i < 2; ++i) {      // B: 2 passes x 64 rows (bf16, 16KB)
      const int r = i * 64 + rB;
      gload_lds16(Wfb + (long)(col0 + r) * DIM + k0 + swzB,
                  base + 32768 + (i * 64 + wid * 8) * 128);
    }
  };

  auto COMPUTE = [&](int buf) {
    const float*  Ab = (const float*)&lds[buf][0];
    const ushort* Bb = (const ushort*)&lds[buf][32768];
#pragma unroll
    for (int kk = 0; kk < 2; ++kk) {
      const int j = kk * 4 + (lane >> 4);            // k-chunk 0..7 (8 floats)
      bf16x8 a[2];
#pragma unroll
      for (int m = 0; m < 2; ++m) {
        const int ra = wrow + m * 16 + (lane & 15);
        const int s  = ra & 7;
        f32x4 lo = *(const f32x4*)(Ab + ra * 64 + (((2 * j)     ^ s) << 2));
        f32x4 hi = *(const f32x4*)(Ab + ra * 64 + (((2 * j + 1) ^ s) << 2));
        a[m] = pack8(lo, hi);
      }
#pragma unroll
      for (int n = 0; n < 4; ++n) {
        const int rb = wcol + n * 16 + (lane & 15);
        bf16x8 b = *(const bf16x8*)(Bb + rb * 64 + ((j ^ (rb & 7)) << 3));
#pragma unroll
        for (int m = 0; m < 2; ++m)
          acc[m][n] = __builtin_amdgcn_mfma_f32_16x16x32_bf16(a[m], b, acc[m][n], 0, 0, 0);
      }
    }
  };

  STAGE(0, 0);
  STAGE(1, 1);
  int c = 0;
#pragma unroll 1
  for (int t = 0; t < 12; ++t) {
    if (t < 10) {
      const int nb = (c == 0) ? 2 : c - 1;           // (t+2)%3
      STAGE(t + 2, nb);
      asm volatile("s_waitcnt vmcnt(12)" ::: "memory"); // tile t landed; t+1,t+2 in flight
    } else if (t == 10) {
      asm volatile("s_waitcnt vmcnt(6)" ::: "memory");
    } else {
      asm volatile("s_waitcnt vmcnt(0)" ::: "memory");
    }
    __builtin_amdgcn_s_barrier();
    __builtin_amdgcn_sched_barrier(0);
    COMPUTE(c);
    __builtin_amdgcn_sched_barrier(0);
    __builtin_amdgcn_s_barrier();
    c = (c == 2) ? 0 : c + 1;
  }

  const int lq = lane >> 4;
  const int lc = lane & 15;
#pragma unroll
  for (int n = 0; n < 4; ++n) {
    const int cg = col0 + wcol + n * 16 + lc;
    const float bv = bias[cg];
#pragma unroll
    for (int m = 0; m < 2; ++m) {
      const int rg = row0 + wrow + m * 16 + lq * 4;
#pragma unroll
      for (int r2 = 0; r2 < 4; ++r2) {
        float v = acc[m][n][r2] + bv;
        v = fmaxf(v, 0.0f);
        H[(long)(rg + r2) * DIM + cg] = f2b(v);
      }
    }
  }
}

// ---------------- K2: logits[n] = sum_k relu(h·Wa^T)·sigmoid(h·Wb^T)·Wc -------
__global__ __launch_bounds__(512)
void gate_kernel(const ushort* __restrict__ Hm, const ushort* __restrict__ Wa,
                 const ushort* __restrict__ Wb, const float* __restrict__ Wc,
                 float* __restrict__ logits) {
  __shared__ ushort Hs [128 * 64];
  __shared__ ushort Was[128 * 64];
  __shared__ ushort Wbs[128 * 64];
  const int tid  = threadIdx.x;
  const int wid  = tid >> 6;           // 0..7
  const int lane = tid & 63;
  const int row0 = blockIdx.x * 128;

  f32x4 fa[8] = {};
  f32x4 fb[8] = {};

  const int ld_r = lane >> 3;
  const int ld_c = (lane & 7) * 8;

  for (int k0 = 0; k0 < DIM; k0 += 64) {
    __syncthreads();
#pragma unroll
    for (int i = 0; i < 2; ++i) {
      const int ch = i * 8 + wid;      // 0..15
      const int r  = ch * 8 + ld_r;    // 0..127
      gload_lds16(Hm + (long)(row0 + r) * DIM + k0 + ld_c, Hs  + ch * 512);
      gload_lds16(Wa + (long)r * DIM        + k0 + ld_c, Was + ch * 512);
      gload_lds16(Wb + (long)r * DIM        + k0 + ld_c, Wbs + ch * 512);
    }
    __syncthreads();
#pragma unroll
    for (int kk = 0; kk < 2; ++kk) {
      const int kc = kk * 32 + (lane >> 4) * 8;
      bf16x8 h = *(const bf16x8*)(Hs + (wid * 16 + (lane & 15)) * 64 + kc);
#pragma unroll
      for (int n = 0; n < 8; ++n) {
        bf16x8 wa = *(const bf16x8*)(Was + (n * 16 + (lane & 15)) * 64 + kc);
        bf16x8 wb = *(const bf16x8*)(Wbs + (n * 16 + (lane & 15)) * 64 + kc);
        fa[n] = __builtin_amdgcn_mfma_f32_16x16x32_bf16(h, wa, fa[n], 0, 0, 0);
        fb[n] = __builtin_amdgcn_mfma_f32_16x16x32_bf16(h, wb, fb[n], 0, 0, 0);
      }
    }
  }

  const int lc = lane & 15;
  const int lq = lane >> 4;
  float g[4];
#pragma unroll
  for (int r = 0; r < 4; ++r) {
    float s = 0.f;
#pragma unroll
    for (int n = 0; n < 8; ++n) {
      float av = fmaxf(fa[n][r], 0.f);
      float sg = 1.f / (1.f + expf(-fb[n][r]));
      s += av * sg * Wc[n * 16 + lc];
    }
    s += __shfl_xor(s, 1);
    s += __shfl_xor(s, 2);
    s += __shfl_xor(s, 4);
    s += __shfl_xor(s, 8);
    g[r] = s;
  }
  if (lc == 0) {
    const int rbase = row0 + wid * 16 + lq * 4;
#pragma unroll
    for (int r = 0; r < 4; ++r) {
      const int nidx = rbase + r;
      if (nidx < NPTS) logits[nidx] = g[r];
    }
  }
}

// ---------------- K3a: per-block softmax partials (49 blocks x 1024) ----------
__global__ __launch_bounds__(1024)
void softmax_part_kernel(const float* __restrict__ logits, float* __restrict__ part2) {
  __shared__ float red[1024];
  const int tid = threadIdx.x;
  const int n = blockIdx.x * 1024 + tid;
  const float v = (n < NPTS) ? logits[n] : -1e30f;
  red[tid] = v; __syncthreads();
  for (int s = 512; s > 0; s >>= 1) {
    if (tid < s) red[tid] = fmaxf(red[tid], red[tid + s]);
    __syncthreads();
  }
  const float m = red[0];
  __syncthreads();
  red[tid] = (n < NPTS) ? expf(v - m) : 0.f;
  __syncthreads();
  for (int s = 512; s > 0; s >>= 1) {
    if (tid < s) red[tid] += red[tid + s];
    __syncthreads();
  }
  if (tid == 0) { part2[blockIdx.x * 2] = m; part2[blockIdx.x * 2 + 1] = red[0]; }
}

// ---------------- K3b: combine partials (1 wave, deterministic trees) ---------
__global__ void softmax_comb_kernel(const float* __restrict__ part2,
                                    float* __restrict__ stats) {
  const int l = threadIdx.x;           // 0..63
  float m = (l < NSMB) ? part2[l * 2]     : -1e30f;
  float s = (l < NSMB) ? part2[l * 2 + 1] : 0.f;
  float M = m;
  for (int o = 32; o > 0; o >>= 1) M = fmaxf(M, __shfl_xor(M, o));
  float sc = s * expf(m - M);          // padding: 0 * 0 = 0
  for (int o = 32; o > 0; o >>= 1) sc += __shfl_xor(sc, o);
  if (l == 0) { stats[0] = M; stats[1] = sc; }
}

// ---------------- K4: partial[b][d] = sum_{n in chunk} exp(l_n - m) * h[n][d] --
__global__ __launch_bounds__(192)
void weighted_partial_kernel(const ushort* __restrict__ Hm, const float* __restrict__ logits,
                             const float* __restrict__ stats, float* __restrict__ part) {
  __shared__ float w[128];
  const int b = blockIdx.x, tid = threadIdx.x;
  const int n0 = b * 128;
  if (tid < 128) {
    const int n = n0 + tid;
    w[tid] = (n < NPTS) ? expf(logits[n] - stats[0]) : 0.f;
  }
  __syncthreads();
  float4 acc = {0.f, 0.f, 0.f, 0.f};
  const ushort* hp = Hm + (long)n0 * DIM + tid * 4;
#pragma unroll 4
  for (int r = 0; r < 128; ++r) {
    const float wr = w[r];
    ushort4 v = *(const ushort4*)(hp + (long)r * DIM);
    acc.x += wr * b2f(v.x);
    acc.y += wr * b2f(v.y);
    acc.z += wr * b2f(v.z);
    acc.w += wr * b2f(v.w);
  }
  ((float4*)(part + (long)b * DIM))[tid] = acc;
}

// ---------------- K5: out[d] = (sum_b part[b][d]) / sum_exp --------------------
__global__ void final_reduce_kernel(const float* __restrict__ part,
                                    const float* __restrict__ stats,
                                    float* __restrict__ out) {
  const int c = blockIdx.x * blockDim.x + threadIdx.x;
  if (c >= DIM) return;
  float s = 0.f;
  for (int b = 0; b < NRB; ++b) s += part[(long)b * DIM + c];
  out[c] = s / stats[1];
}

extern "C" void kernel_launch(void* const* d_in, const int* in_sizes, int n_in,
                              void* d_out, int out_size, void* d_ws, size_t ws_size,
                              hipStream_t stream) {
  const float* x  = (const float*)d_in[0];
  const float* Wf = (const float*)d_in[1];
  const float* bf = (const float*)d_in[2];
  const float* Wa = (const float*)d_in[3];
  const float* Wb = (const float*)d_in[4];
  const float* Wc = (const float*)d_in[5];
  float* out = (float*)d_out;

  char* p = (char*)d_ws;
  ushort* hb  = (ushort*)p; p += (size_t)NPAD * DIM * 2;   // 77.1 MB
  ushort* wfb = (ushort*)p; p += (size_t)DIM * DIM * 2;
  ushort* wab = (ushort*)p; p += (size_t)DATT * DIM * 2;
  ushort* wbb = (ushort*)p; p += (size_t)DATT * DIM * 2;
  float* logits = (float*)p; p += (size_t)NPAD * 4;
  float* stats  = (float*)p; p += 256;
  float* part2  = (float*)p; p += 1024;
  float* part   = (float*)p; p += (size_t)NRB * DIM * 4;

  cvt_weights_kernel<<<384, 256, 0, stream>>>(Wf, Wa, Wb, wfb, wab, wbb);

  gemm_h_fused<<<392 * 6, 512, 0, stream>>>(x, wfb, bf, hb);
  gate_kernel<<<NRB, 512, 0, stream>>>(hb, wab, wbb, Wc, logits);
  softmax_part_kernel<<<NSMB, 1024, 0, stream>>>(logits, part2);
  softmax_comb_kernel<<<1, 64, 0, stream>>>(part2, stats);
  weighted_partial_kernel<<<NRB, 192, 0, stream>>>(hb, logits, stats, part);
  final_reduce_kernel<<<3, 256, 0, stream>>>(part, stats, out);
}

// Round 7
// 210.568 us; speedup vs baseline: 1.1608x; 1.1608x over previous
//
#include <hip/hip_runtime.h>
#include <hip/hip_bf16.h>
#include <stdint.h>

#define DEVINL __device__ __forceinline__

using bf16x8 = __attribute__((ext_vector_type(8))) short;
using f32x4  = __attribute__((ext_vector_type(4))) float;

static constexpr int NPTS = 50000;
static constexpr int NPAD = 50176;         // 392 * 128
static constexpr int DIM  = 768;
static constexpr int DATT = 128;
static constexpr int NRB  = NPAD / 128;    // 392 row blocks (gate / partial)
static constexpr int NSMB = 49;            // softmax partial blocks (49*1024 = 50176)

DEVINL ushort f2b(float f) {               // RNE float->bf16 (finite inputs)
  uint32_t u = __float_as_uint(f);
  u += 0x7fffu + ((u >> 16) & 1u);
  return (ushort)(u >> 16);
}
DEVINL float b2f(ushort u) { return __uint_as_float(((uint32_t)u) << 16); }

DEVINL void gload_lds16(const void* g, void* l) {
  __builtin_amdgcn_global_load_lds((const __attribute__((address_space(1))) void*)g,
                                   (__attribute__((address_space(3))) void*)l,
                                   16, 0, 0);
}

DEVINL uint32_t cvtpk(float lo, float hi) {
  union { __hip_bfloat162 h2; uint32_t u; } c;
  c.h2 = __float22bfloat162_rn(float2{lo, hi});
  return c.u;
}
DEVINL bf16x8 pack8(f32x4 lo, f32x4 hi) {
  union { uint32_t u[4]; bf16x8 v; } r;
  r.u[0] = cvtpk(lo[0], lo[1]);
  r.u[1] = cvtpk(lo[2], lo[3]);
  r.u[2] = cvtpk(hi[0], hi[1]);
  r.u[3] = cvtpk(hi[2], hi[3]);
  return r.v;
}

// ---------------- K0b: fp32 -> bf16 for the three weight matrices (one launch)
__global__ void cvt_weights_kernel(const float* __restrict__ Wf, const float* __restrict__ Wa,
                                   const float* __restrict__ Wb,
                                   ushort* __restrict__ wfb, ushort* __restrict__ wab,
                                   ushort* __restrict__ wbb) {
  const int NF = DIM * DIM / 8, NA = DATT * DIM / 8;
  int i = blockIdx.x * blockDim.x + threadIdx.x;
  const float* src; ushort* dst; int j;
  if (i < NF)               { src = Wf; dst = wfb; j = i; }
  else if (i < NF + NA)     { src = Wa; dst = wab; j = i - NF; }
  else if (i < NF + 2 * NA) { src = Wb; dst = wbb; j = i - NF - NA; }
  else return;
  const float4* s4 = (const float4*)src;
  float4 v0 = s4[(long)j * 2];
  float4 v1 = s4[(long)j * 2 + 1];
  ushort4 o0 = { f2b(v0.x), f2b(v0.y), f2b(v0.z), f2b(v0.w) };
  ushort4 o1 = { f2b(v1.x), f2b(v1.y), f2b(v1.z), f2b(v1.w) };
  ((ushort4*)dst)[(long)j * 2]     = o0;
  ((ushort4*)dst)[(long)j * 2 + 1] = o1;
}

// ---------------- K1: h = relu(x @ Wf^T + bias), fused fp32->bf16 on A --------
// BM=128, BN=256, BK=64; 8 waves (2M x 4N), wave tile 64x64 (32 MFMA/step).
// A staged fp32 via global_load_lds (zero staging VGPRs), cvt at fragment read.
// Double buffer (2 x 64KB). COUNTED pipeline: issue STAGE(t+1), then vmcnt(8)
// (= the 8 just-issued loads allowed in flight; stage(t) drained), leading
// barrier, COMPUTE(t), trailing barrier. stage(t+1) writes buf[(t+1)&1] whose
// last reads (compute(t-1)) are fenced by t-1's trailing barrier; ds_read
// results are consumed by MFMAs before the trailing barrier -> race-free.
// A swizzle: 16-slot XOR (&15) both sides -> <=2-way LDS read (free).
__global__ __launch_bounds__(512, 2)
void gemm_h_fused(const float* __restrict__ X, const ushort* __restrict__ Wfb,
                  const float* __restrict__ bias, ushort* __restrict__ H) {
  __shared__ char lds[2][65536];

  const int tid  = threadIdx.x;
  const int wid  = tid >> 6;           // 0..7
  const int lane = tid & 63;

  const int bid  = blockIdx.x;                       // 0..1175
  const int wgid = (bid & 7) * 147 + (bid >> 3);     // chunked XCD swizzle (1176%8==0)
  const int row0 = (wgid / 3) * 128;
  const int col0 = (wgid % 3) * 256;

  const int wrow = (wid >> 2) * 64;    // 0,64
  const int wcol = (wid & 3) * 64;     // 0,64,128,192

  f32x4 acc[4][4] = {};

  // staging geometry (LDS dests wave-uniform; swizzle on the global source)
  const int rA   = wid * 4 + (lane >> 4);            // A row within pass (0..31)
  const int swzA = ((lane & 15) ^ (rA & 15)) * 4;    // fp32 col offset, 16-slot XOR
  const int rB   = wid * 8 + (lane >> 3);            // B row within pass (0..63)
  const int swzB = ((lane & 7) ^ (rB & 7)) * 8;      // bf16 col offset (16B gran)

  auto STAGE = [&](int t, int buf) {                 // 8 gload_lds per thread
    const int k0 = t * 64;
    char* base = &lds[buf][0];
#pragma unroll
    for (int i = 0; i < 4; ++i) {      // A: 4 passes x 32 rows (fp32, 32KB)
      const int rg  = row0 + i * 32 + rA;
      const int src = rg < NPTS ? rg : NPTS - 1;     // clamp; masked downstream
      gload_lds16(X + (long)src * DIM + k0 + swzA, base + (i * 32 + wid * 4) * 256);
    }
#pragma unroll
    for (int i = 0; i < 4; ++i) {      // B: 4 passes x 64 rows (bf16, 32KB)
      const int r = i * 64 + rB;
      gload_lds16(Wfb + (long)(col0 + r) * DIM + k0 + swzB,
                  base + 32768 + (i * 64 + wid * 8) * 128);
    }
  };

  auto COMPUTE = [&](int buf) {
    const float*  Ab = (const float*)&lds[buf][0];
    const ushort* Bb = (const ushort*)&lds[buf][32768];
#pragma unroll
    for (int kk = 0; kk < 2; ++kk) {
      const int j = kk * 4 + (lane >> 4);            // k-chunk 0..7 (8 floats)
      bf16x8 a[4];
#pragma unroll
      for (int m = 0; m < 4; ++m) {
        const int ra = wrow + m * 16 + (lane & 15);
        const int s  = ra & 15;
        f32x4 lo = *(const f32x4*)(Ab + ra * 64 + (((2 * j)     ^ s) << 2));
        f32x4 hi = *(const f32x4*)(Ab + ra * 64 + (((2 * j + 1) ^ s) << 2));
        a[m] = pack8(lo, hi);
      }
#pragma unroll
      for (int n = 0; n < 4; ++n) {
        const int rb = wcol + n * 16 + (lane & 15);
        bf16x8 b = *(const bf16x8*)(Bb + rb * 64 + ((j ^ (rb & 7)) << 3));
#pragma unroll
        for (int m = 0; m < 4; ++m)
          acc[m][n] = __builtin_amdgcn_mfma_f32_16x16x32_bf16(a[m], b, acc[m][n], 0, 0, 0);
      }
    }
  };

  STAGE(0, 0);
#pragma unroll 1
  for (int t = 0; t < 12; ++t) {
    if (t < 11) {
      STAGE(t + 1, (t + 1) & 1);                     // prefetch next tile
      asm volatile("s_waitcnt vmcnt(8)" ::: "memory"); // tile t landed; t+1 in flight
    } else {
      asm volatile("s_waitcnt vmcnt(0)" ::: "memory");
    }
    __builtin_amdgcn_s_barrier();
    __builtin_amdgcn_sched_barrier(0);
    COMPUTE(t & 1);
    __builtin_amdgcn_sched_barrier(0);
    __builtin_amdgcn_s_barrier();
  }

  const int lq = lane >> 4;
  const int lc = lane & 15;
#pragma unroll
  for (int n = 0; n < 4; ++n) {
    const int cg = col0 + wcol + n * 16 + lc;
    const float bv = bias[cg];
#pragma unroll
    for (int m = 0; m < 4; ++m) {
      const int rg = row0 + wrow + m * 16 + lq * 4;
#pragma unroll
      for (int r2 = 0; r2 < 4; ++r2) {
        float v = acc[m][n][r2] + bv;
        v = fmaxf(v, 0.0f);
        H[(long)(rg + r2) * DIM + cg] = f2b(v);
      }
    }
  }
}

// ---------------- K2: logits[n] = sum_k relu(h·Wa^T)·sigmoid(h·Wb^T)·Wc -------
__global__ __launch_bounds__(512)
void gate_kernel(const ushort* __restrict__ Hm, const ushort* __restrict__ Wa,
                 const ushort* __restrict__ Wb, const float* __restrict__ Wc,
                 float* __restrict__ logits) {
  __shared__ ushort Hs [128 * 64];
  __shared__ ushort Was[128 * 64];
  __shared__ ushort Wbs[128 * 64];
  const int tid  = threadIdx.x;
  const int wid  = tid >> 6;           // 0..7
  const int lane = tid & 63;
  const int row0 = blockIdx.x * 128;

  f32x4 fa[8] = {};
  f32x4 fb[8] = {};

  const int ld_r = lane >> 3;
  const int ld_c = (lane & 7) * 8;

  for (int k0 = 0; k0 < DIM; k0 += 64) {
    __syncthreads();
#pragma unroll
    for (int i = 0; i < 2; ++i) {
      const int ch = i * 8 + wid;      // 0..15
      const int r  = ch * 8 + ld_r;    // 0..127
      gload_lds16(Hm + (long)(row0 + r) * DIM + k0 + ld_c, Hs  + ch * 512);
      gload_lds16(Wa + (long)r * DIM        + k0 + ld_c, Was + ch * 512);
      gload_lds16(Wb + (long)r * DIM        + k0 + ld_c, Wbs + ch * 512);
    }
    __syncthreads();
#pragma unroll
    for (int kk = 0; kk < 2; ++kk) {
      const int kc = kk * 32 + (lane >> 4) * 8;
      bf16x8 h = *(const bf16x8*)(Hs + (wid * 16 + (lane & 15)) * 64 + kc);
#pragma unroll
      for (int n = 0; n < 8; ++n) {
        bf16x8 wa = *(const bf16x8*)(Was + (n * 16 + (lane & 15)) * 64 + kc);
        bf16x8 wb = *(const bf16x8*)(Wbs + (n * 16 + (lane & 15)) * 64 + kc);
        fa[n] = __builtin_amdgcn_mfma_f32_16x16x32_bf16(h, wa, fa[n], 0, 0, 0);
        fb[n] = __builtin_amdgcn_mfma_f32_16x16x32_bf16(h, wb, fb[n], 0, 0, 0);
      }
    }
  }

  const int lc = lane & 15;
  const int lq = lane >> 4;
  float g[4];
#pragma unroll
  for (int r = 0; r < 4; ++r) {
    float s = 0.f;
#pragma unroll
    for (int n = 0; n < 8; ++n) {
      float av = fmaxf(fa[n][r], 0.f);
      float sg = 1.f / (1.f + expf(-fb[n][r]));
      s += av * sg * Wc[n * 16 + lc];
    }
    s += __shfl_xor(s, 1);
    s += __shfl_xor(s, 2);
    s += __shfl_xor(s, 4);
    s += __shfl_xor(s, 8);
    g[r] = s;
  }
  if (lc == 0) {
    const int rbase = row0 + wid * 16 + lq * 4;
#pragma unroll
    for (int r = 0; r < 4; ++r) {
      const int nidx = rbase + r;
      if (nidx < NPTS) logits[nidx] = g[r];
    }
  }
}

// ---------------- K3a: per-block softmax partials (49 blocks x 1024) ----------
__global__ __launch_bounds__(1024)
void softmax_part_kernel(const float* __restrict__ logits, float* __restrict__ part2) {
  __shared__ float red[1024];
  const int tid = threadIdx.x;
  const int n = blockIdx.x * 1024 + tid;
  const float v = (n < NPTS) ? logits[n] : -1e30f;
  red[tid] = v; __syncthreads();
  for (int s = 512; s > 0; s >>= 1) {
    if (tid < s) red[tid] = fmaxf(red[tid], red[tid + s]);
    __syncthreads();
  }
  const float m = red[0];
  __syncthreads();
  red[tid] = (n < NPTS) ? expf(v - m) : 0.f;
  __syncthreads();
  for (int s = 512; s > 0; s >>= 1) {
    if (tid < s) red[tid] += red[tid + s];
    __syncthreads();
  }
  if (tid == 0) { part2[blockIdx.x * 2] = m; part2[blockIdx.x * 2 + 1] = red[0]; }
}

// ---------------- K3b: combine partials (1 wave, deterministic trees) ---------
__global__ void softmax_comb_kernel(const float* __restrict__ part2,
                                    float* __restrict__ stats) {
  const int l = threadIdx.x;           // 0..63
  float m = (l < NSMB) ? part2[l * 2]     : -1e30f;
  float s = (l < NSMB) ? part2[l * 2 + 1] : 0.f;
  float M = m;
  for (int o = 32; o > 0; o >>= 1) M = fmaxf(M, __shfl_xor(M, o));
  float sc = s * expf(m - M);          // padding: 0 * 0 = 0
  for (int o = 32; o > 0; o >>= 1) sc += __shfl_xor(sc, o);
  if (l == 0) { stats[0] = M; stats[1] = sc; }
}

// ---------------- K4: partial[b][d] = sum_{n in chunk} exp(l_n - m) * h[n][d] --
__global__ __launch_bounds__(192)
void weighted_partial_kernel(const ushort* __restrict__ Hm, const float* __restrict__ logits,
                             const float* __restrict__ stats, float* __restrict__ part) {
  __shared__ float w[128];
  const int b = blockIdx.x, tid = threadIdx.x;
  const int n0 = b * 128;
  if (tid < 128) {
    const int n = n0 + tid;
    w[tid] = (n < NPTS) ? expf(logits[n] - stats[0]) : 0.f;
  }
  __syncthreads();
  float4 acc = {0.f, 0.f, 0.f, 0.f};
  const ushort* hp = Hm + (long)n0 * DIM + tid * 4;
#pragma unroll 4
  for (int r = 0; r < 128; ++r) {
    const float wr = w[r];
    ushort4 v = *(const ushort4*)(hp + (long)r * DIM);
    acc.x += wr * b2f(v.x);
    acc.y += wr * b2f(v.y);
    acc.z += wr * b2f(v.z);
    acc.w += wr * b2f(v.w);
  }
  ((float4*)(part + (long)b * DIM))[tid] = acc;
}

// ---------------- K5: out[d] = (sum_b part[b][d]) / sum_exp --------------------
__global__ void final_reduce_kernel(const float* __restrict__ part,
                                    const float* __restrict__ stats,
                                    float* __restrict__ out) {
  const int c = blockIdx.x * blockDim.x + threadIdx.x;
  if (c >= DIM) return;
  float s = 0.f;
  for (int b = 0; b < NRB; ++b) s += part[(long)b * DIM + c];
  out[c] = s / stats[1];
}

extern "C" void kernel_launch(void* const* d_in, const int* in_sizes, int n_in,
                              void* d_out, int out_size, void* d_ws, size_t ws_size,
                              hipStream_t stream) {
  const float* x  = (const float*)d_in[0];
  const float* Wf = (const float*)d_in[1];
  const float* bf = (const float*)d_in[2];
  const float* Wa = (const float*)d_in[3];
  const float* Wb = (const float*)d_in[4];
  const float* Wc = (const float*)d_in[5];
  float* out = (float*)d_out;

  char* p = (char*)d_ws;
  ushort* hb  = (ushort*)p; p += (size_t)NPAD * DIM * 2;   // 77.1 MB
  ushort* wfb = (ushort*)p; p += (size_t)DIM * DIM * 2;
  ushort* wab = (ushort*)p; p += (size_t)DATT * DIM * 2;
  ushort* wbb = (ushort*)p; p += (size_t)DATT * DIM * 2;
  float* logits = (float*)p; p += (size_t)NPAD * 4;
  float* stats  = (float*)p; p += 256;
  float* part2  = (float*)p; p += 1024;
  float* part   = (float*)p; p += (size_t)NRB * DIM * 4;

  cvt_weights_kernel<<<384, 256, 0, stream>>>(Wf, Wa, Wb, wfb, wab, wbb);

  gemm_h_fused<<<392 * 3, 512, 0, stream>>>(x, wfb, bf, hb);
  gate_kernel<<<NRB, 512, 0, stream>>>(hb, wab, wbb, Wc, logits);
  softmax_part_kernel<<<NSMB, 1024, 0, stream>>>(logits, part2);
  softmax_comb_kernel<<<1, 64, 0, stream>>>(part2, stats);
  weighted_partial_kernel<<<NRB, 192, 0, stream>>>(hb, logits, stats, part);
  final_reduce_kernel<<<3, 256, 0, stream>>>(part, stats, out);
}